// Round 9
// baseline (203.146 us; speedup 1.0000x reference)
//
#include <hip/hip_runtime.h>
#include <hip/hip_bf16.h>
#include <stdint.h>

#define B_ 2
#define N_ 2048
#define DIM_ 1024
#define HEADS_ 16
#define DH_ 64
#define EPS_ 1e-5f

typedef __attribute__((ext_vector_type(4))) float f32x4;
typedef __attribute__((ext_vector_type(8))) float f32x8;
typedef __attribute__((ext_vector_type(16))) float f32x16;
typedef __attribute__((ext_vector_type(8))) __bf16 bf16x8;
typedef __attribute__((ext_vector_type(4))) unsigned int u32x4;
typedef __attribute__((ext_vector_type(2))) unsigned int u32x2;

__device__ __forceinline__ f32x4 mfma16(bf16x8 a, bf16x8 b, f32x4 c) {
  return __builtin_amdgcn_mfma_f32_16x16x32_bf16(a, b, c, 0, 0, 0);
}

__device__ __forceinline__ f32x16 mfma32(bf16x8 a, bf16x8 b, f32x16 c) {
  return __builtin_amdgcn_mfma_f32_32x32x16_bf16(a, b, c, 0, 0, 0);
}

__device__ __forceinline__ unsigned short f2bf(float x) {
  unsigned int u = __builtin_bit_cast(unsigned int, x);
  u += 0x7fffu + ((u >> 16) & 1u);
  return (unsigned short)(u >> 16);
}

__device__ __forceinline__ unsigned int cvt_pk_bf16(float lo, float hi) {
  unsigned int r;
  asm("v_cvt_pk_bf16_f32 %0, %1, %2" : "=v"(r) : "v"(lo), "v"(hi));
  return r;
}

__device__ __forceinline__ float uasf(unsigned int u) { return __builtin_bit_cast(float, u); }
__device__ __forceinline__ unsigned int fasu(float f) { return __builtin_bit_cast(unsigned int, f); }

__device__ __forceinline__ bf16x8 ld_frag(const unsigned short* p) {
  u32x4 v = *reinterpret_cast<const u32x4*>(p);
  return __builtin_bit_cast(bf16x8, v);
}

__device__ __forceinline__ void gload_lds16(const unsigned short* g, unsigned short* l) {
  __builtin_amdgcn_global_load_lds((const __attribute__((address_space(1))) void*)g,
                                   (__attribute__((address_space(3))) void*)l, 16, 0, 0);
}

// ---------------- LayerNorm over sequence axis ----------------
__global__ __launch_bounds__(256) void ln_part(const float* __restrict__ x,
                                               float* __restrict__ ps,
                                               float* __restrict__ pss) {
  const int d = blockIdx.x * 256 + threadIdx.x;
  const int b = blockIdx.y >> 4, sp = blockIdx.y & 15;
  const float* xp = x + (size_t)(b * N_ + sp * 128) * DIM_ + d;
  float s = 0.f, ss = 0.f;
  for (int i = 0; i < 128; ++i) {
    float v = xp[(size_t)i * DIM_];
    s += v;
    ss += v * v;
  }
  int c = b * DIM_ + d;
  ps[sp * (B_ * DIM_) + c] = s;
  pss[sp * (B_ * DIM_) + c] = ss;
}

__global__ void ln_fin(const float* __restrict__ ps, const float* __restrict__ pss,
                       const float* __restrict__ g, float* __restrict__ meanA,
                       float* __restrict__ sclA) {
  int c = blockIdx.x * 256 + threadIdx.x;
  float s = 0.f, ss = 0.f;
#pragma unroll
  for (int sp = 0; sp < 16; ++sp) {
    s += ps[sp * (B_ * DIM_) + c];
    ss += pss[sp * (B_ * DIM_) + c];
  }
  float m = s * (1.f / N_);
  float v = ss * (1.f / N_) - m * m;
  meanA[c] = m;
  sclA[c] = rsqrtf(fmaxf(v, EPS_)) * g[c & (DIM_ - 1)];
}

__global__ __launch_bounds__(256) void ln_apply(const float* __restrict__ x,
                                                const float* __restrict__ meanA,
                                                const float* __restrict__ sclA,
                                                unsigned short* __restrict__ xn) {
  size_t t = (size_t)blockIdx.x * 256 + threadIdx.x;
  size_t base = t * 8;
  int d0 = (int)(base & (DIM_ - 1));
  int b = base >= (size_t)N_ * DIM_;
  int c = b * DIM_ + d0;
  const float4* xp = reinterpret_cast<const float4*>(x + base);
  const float4* mp = reinterpret_cast<const float4*>(meanA + c);
  const float4* sp = reinterpret_cast<const float4*>(sclA + c);
  float4 x0 = xp[0], x1 = xp[1];
  float4 m0 = mp[0], m1 = mp[1];
  float4 s0 = sp[0], s1 = sp[1];
  union {
    unsigned short u[8];
    u32x4 v;
  } o;
  o.u[0] = f2bf((x0.x - m0.x) * s0.x);
  o.u[1] = f2bf((x0.y - m0.y) * s0.y);
  o.u[2] = f2bf((x0.z - m0.z) * s0.z);
  o.u[3] = f2bf((x0.w - m0.w) * s0.w);
  o.u[4] = f2bf((x1.x - m1.x) * s1.x);
  o.u[5] = f2bf((x1.y - m1.y) * s1.y);
  o.u[6] = f2bf((x1.z - m1.z) * s1.z);
  o.u[7] = f2bf((x1.w - m1.w) * s1.w);
  *reinterpret_cast<u32x4*>(xn + base) = o.v;
}

// ---------------- fp32 -> bf16 weight cast (optional scale) ----------------
__global__ __launch_bounds__(256) void cast_bf16(const float* __restrict__ src,
                                                 unsigned short* __restrict__ dst, float scale) {
  size_t t = (size_t)blockIdx.x * 256 + threadIdx.x;
  size_t base = t * 8;
  const float4* sp = reinterpret_cast<const float4*>(src + base);
  float4 a = sp[0], b4 = sp[1];
  union {
    unsigned short u[8];
    u32x4 v;
  } o;
  o.u[0] = f2bf(a.x * scale);
  o.u[1] = f2bf(a.y * scale);
  o.u[2] = f2bf(a.z * scale);
  o.u[3] = f2bf(a.w * scale);
  o.u[4] = f2bf(b4.x * scale);
  o.u[5] = f2bf(b4.y * scale);
  o.u[6] = f2bf(b4.z * scale);
  o.u[7] = f2bf(b4.w * scale);
  *reinterpret_cast<u32x4*>(dst + base) = o.v;
}

// ---------------- GEMM: C[M,Nc] = A[M,K]bf16 * W[Nc,K]bf16^T ----------------
template <bool OUT_F32>
__global__ __launch_bounds__(256) void gemm_bt(const unsigned short* __restrict__ A,
                                               const unsigned short* __restrict__ W,
                                               void* __restrict__ Cout, int K, int ldc) {
  __shared__ unsigned short sA[128 * 64];
  __shared__ unsigned short sB[128 * 64];
  const int tid = threadIdx.x, lane = tid & 63, w = tid >> 6;
  const int wm = w >> 1, wn = w & 1;
  const int l15 = lane & 15, l4 = lane >> 4;
  const int m0 = blockIdx.y * 128, n0 = blockIdx.x * 128;
  f32x4 acc[4][4] = {};
  for (int kt = 0; kt < K; kt += 64) {
    __syncthreads();
#pragma unroll
    for (int p = 0; p < 4; ++p) {
      int flat = p * 256 + tid;
      int row = flat >> 3, c = flat & 7;
      int cs = c ^ (row & 7);
      gload_lds16(A + (size_t)(m0 + row) * K + kt + cs * 8, sA + (size_t)(p * 256 + w * 64) * 8);
      gload_lds16(W + (size_t)(n0 + row) * K + kt + cs * 8, sB + (size_t)(p * 256 + w * 64) * 8);
    }
    __syncthreads();
#pragma unroll
    for (int kk = 0; kk < 2; ++kk) {
      bf16x8 af[4], bfr[4];
#pragma unroll
      for (int i = 0; i < 4; ++i) {
        int rowA = wm * 64 + i * 16 + l15;
        af[i] = ld_frag(sA + rowA * 64 + (((kk * 4 + l4) ^ (rowA & 7)) * 8));
        int rowB = wn * 64 + i * 16 + l15;
        bfr[i] = ld_frag(sB + rowB * 64 + (((kk * 4 + l4) ^ (rowB & 7)) * 8));
      }
#pragma unroll
      for (int i = 0; i < 4; ++i)
#pragma unroll
        for (int j = 0; j < 4; ++j) acc[i][j] = mfma16(af[i], bfr[j], acc[i][j]);
    }
  }
#pragma unroll
  for (int i = 0; i < 4; ++i)
#pragma unroll
    for (int j = 0; j < 4; ++j)
#pragma unroll
      for (int r = 0; r < 4; ++r) {
        size_t off =
            (size_t)(m0 + wm * 64 + i * 16 + l4 * 4 + r) * ldc + (n0 + wn * 64 + j * 16 + l15);
        if (OUT_F32)
          ((float*)Cout)[off] = acc[i][j][r];
        else
          ((unsigned short*)Cout)[off] = f2bf(acc[i][j][r]);
      }
}

// ---------------- V transpose: qkv v-block -> Vt[b][h][dh][n] ----------------
__global__ __launch_bounds__(256) void transpose_v(const unsigned short* __restrict__ qkv,
                                                   unsigned short* __restrict__ Vt) {
  __shared__ unsigned short tt[64][65];
  const int tid = threadIdx.x;
  const int h = blockIdx.y >> 1, b = blockIdx.y & 1;
  const int n0 = blockIdx.x * 64;
  const unsigned short* src = qkv + (size_t)(b * N_ + n0) * 3072 + 2048 + h * 64;
#pragma unroll
  for (int i = 0; i < 16; ++i) {
    int idx = i * 256 + tid;
    int r = idx >> 6, c = idx & 63;
    tt[r][c] = src[(size_t)r * 3072 + c];
  }
  __syncthreads();
  unsigned short* dst = Vt + (size_t)(b * HEADS_ + h) * 64 * N_ + n0;
#pragma unroll
  for (int i = 0; i < 16; ++i) {
    int idx = i * 256 + tid;
    int dh = idx >> 6, nn = idx & 63;
    dst[(size_t)dh * N_ + nn] = tt[nn][dh];
  }
}

// ---------------- Flash attention (32x32 swapped, in-register softmax+P) ----
// 4 waves x 32 q-rows. S^T[key][q] = K.Q^T via mfma_32x32x16 (A=K, B=Q),
// C-operand = bias^T. C-layout (m74/m101): col=q=lane&31,
// row=key=(reg&3)+8*(reg>>2)+4*(lane>>5). Lane pair l <-> l^32 shares q and
// splits keys -> softmax fully in-register + ONE permlane32_swap per reduce.
// P routed to the PV B-operand in-register via cvt_pk + permlane32_swap:
// semantics ret[0][l<32]=a[l], ret[0][l>=32]=b[l-32], ret[1][l<32]=a[l+32],
// ret[1][l>=32]=b[l]  =>  rX = swap(low_keys_word, high_keys_word) and
// frag = [rA[0], rB[0], rA[1], rB[1]]  (HK recipe, r272).
__global__ __launch_bounds__(256, 2) void flash_attn(const unsigned short* __restrict__ qkv,
                                                     const float* __restrict__ bias,
                                                     const unsigned short* __restrict__ Vt,
                                                     unsigned short* __restrict__ Oatt) {
  __shared__ unsigned short sK[2][64 * 64];
  __shared__ unsigned short sV[2][64 * 64];

  const int tid = threadIdx.x, lane = tid & 63, w = tid >> 6;  // w in 0..3
  const int l31 = lane & 31, hi = lane >> 5;
  // XCD swizzle: bh = id&31 -> (b,h); id%8 = h%8 so both b of a head (and all
  // its i-blocks) share an XCD.
  const int r = blockIdx.x;
  const int bh = r & 31, iblk = r >> 5;
  const int h = bh & 15, b = bh >> 4;
  const int i0 = iblk * 128;
  const int qbase = i0 + w * 32;

  const unsigned short* Kg = qkv + (size_t)b * N_ * 3072 + 1024 + h * 64;
  const unsigned short* VtB = Vt + (size_t)(b * HEADS_ + h) * 64 * N_;
  // per-lane bias row (q = qbase + l31), key sub-offset 4*hi folded in
  const float* bias_l =
      bias + (size_t)h * N_ * N_ + (size_t)(qbase + l31) * N_ + 4 * hi;

  // staging: 256 threads x 2 chunks each for K and V (64 rows x 8 chunks)
  const int row0 = tid >> 3, c0 = tid & 7;
  const int cs0 = c0 ^ (row0 & 7);
  const unsigned short* KgS = Kg + (size_t)row0 * 3072 + cs0 * 8;
  const unsigned short* VtS = VtB + (size_t)row0 * N_ + cs0 * 8;

#define STAGE(BUF, JN)                                                          \
  gload_lds16(KgS + (size_t)(JN) * 3072, sK[BUF] + w * 512);                    \
  gload_lds16(KgS + (size_t)(JN) * 3072 + 32 * 3072, sK[BUF] + 2048 + w * 512); \
  gload_lds16(VtS + (JN), sV[BUF] + w * 512);                                   \
  gload_lds16(VtS + (JN) + 32 * (size_t)N_, sV[BUF] + 2048 + w * 512);

  // Q B-frags: qfK covers d = K*16 + hi*8 .. +7 for q = qbase + l31
  bf16x8 qf0, qf1, qf2, qf3;
  {
    const unsigned short* Qg =
        qkv + (size_t)(b * N_ + qbase + l31) * 3072 + h * 64 + hi * 8;
    qf0 = ld_frag(Qg);
    qf1 = ld_frag(Qg + 16);
    qf2 = ld_frag(Qg + 32);
    qf3 = ld_frag(Qg + 48);
  }

  f32x16 o0 = {}, o1 = {};      // O^T d-blocks 0..31 / 32..63
  f32x16 sA0, sA1, sB0, sB1;    // score/bias ping-pong (key-blocks 0..31/32..63)
  float m_run = -1e30f, l_run = 0.f;

// load one 32-key bias C-block: C[reg r] = bias[q][OFF + 8*(r>>2) + 4*hi + (r&3)]
#define LDBIAS(DST, OFF)                                                   \
  {                                                                        \
    f32x4 t0 = *reinterpret_cast<const f32x4*>(bias_l + (OFF));            \
    f32x4 t1 = *reinterpret_cast<const f32x4*>(bias_l + (OFF) + 8);        \
    f32x4 t2 = *reinterpret_cast<const f32x4*>(bias_l + (OFF) + 16);       \
    f32x4 t3 = *reinterpret_cast<const f32x4*>(bias_l + (OFF) + 24);       \
    f32x8 u0_ = __builtin_shufflevector(t0, t1, 0, 1, 2, 3, 4, 5, 6, 7);   \
    f32x8 u1_ = __builtin_shufflevector(t2, t3, 0, 1, 2, 3, 4, 5, 6, 7);   \
    DST = __builtin_shufflevector(u0_, u1_, 0, 1, 2, 3, 4, 5, 6, 7, 8, 9,  \
                                  10, 11, 12, 13, 14, 15);                 \
  }

// frag read from swizzled LDS tile: row = RB + l31, 16B chunk CH (logical)
#define FRAG(OUT, SRC, RB, CH)                                          \
  {                                                                     \
    int row_ = (RB) + l31;                                              \
    OUT = ld_frag((SRC) + row_ * 64 + (((CH) ^ (row_ & 7)) * 8));       \
  }

  // prologue: stage K/V tile 0 + bias tile 0 -> sA
  STAGE(0, 0)
  LDBIAS(sA0, 0)
  LDBIAS(sA1, 32)
  __syncthreads();

  const int NT = N_ / 64;

#define TILE_BODY(T, CUR, NXT, S0, S1, S0N, S1N)                               \
  {                                                                            \
    if ((T) + 1 < NT) {                                                        \
      const size_t jn = (size_t)((T) + 1) * 64;                                \
      STAGE(NXT, jn)                                                           \
      __builtin_amdgcn_sched_barrier(0); /* pin gloads oldest in vmem queue */ \
      LDBIAS(S0N, jn)                                                          \
      LDBIAS(S1N, jn + 32)                                                     \
    }                                                                          \
    const unsigned short* sKc = sK[CUR];                                       \
    const unsigned short* sVc = sV[CUR];                                       \
    /* S^T = K Q^T + bias (bias preloaded in S0/S1 = C-operand) */             \
    __builtin_amdgcn_s_setprio(1);                                             \
    {                                                                          \
      bf16x8 kf;                                                               \
      FRAG(kf, sKc, 0, 0 + hi) S0 = mfma32(kf, qf0, S0);                       \
      FRAG(kf, sKc, 0, 2 + hi) S0 = mfma32(kf, qf1, S0);                       \
      FRAG(kf, sKc, 0, 4 + hi) S0 = mfma32(kf, qf2, S0);                       \
      FRAG(kf, sKc, 0, 6 + hi) S0 = mfma32(kf, qf3, S0);                       \
      FRAG(kf, sKc, 32, 0 + hi) S1 = mfma32(kf, qf0, S1);                      \
      FRAG(kf, sKc, 32, 2 + hi) S1 = mfma32(kf, qf1, S1);                      \
      FRAG(kf, sKc, 32, 4 + hi) S1 = mfma32(kf, qf2, S1);                      \
      FRAG(kf, sKc, 32, 6 + hi) S1 = mfma32(kf, qf3, S1);                      \
    }                                                                          \
    __builtin_amdgcn_s_setprio(0);                                             \
    /* online softmax, fully in-register (lane pair l <-> l^32 shares q) */    \
    float mx = S0[0];                                                          \
    _Pragma("unroll") for (int i = 1; i < 16; ++i) mx = fmaxf(mx, S0[i]);      \
    _Pragma("unroll") for (int i = 0; i < 16; ++i) mx = fmaxf(mx, S1[i]);      \
    {                                                                          \
      auto pr_ = __builtin_amdgcn_permlane32_swap(fasu(mx), fasu(mx), false,   \
                                                  false);                      \
      mx = fmaxf(uasf(pr_[0]), uasf(pr_[1]));                                  \
    }                                                                          \
    float mn = fmaxf(m_run, mx);                                               \
    float alpha = __expf(m_run - mn);                                          \
    _Pragma("unroll") for (int i = 0; i < 16; ++i) S0[i] = __expf(S0[i] - mn); \
    _Pragma("unroll") for (int i = 0; i < 16; ++i) S1[i] = __expf(S1[i] - mn); \
    float rs = 0.f;                                                            \
    _Pragma("unroll") for (int i = 0; i < 16; ++i) rs += S0[i];                \
    _Pragma("unroll") for (int i = 0; i < 16; ++i) rs += S1[i];                \
    {                                                                          \
      auto pr_ = __builtin_amdgcn_permlane32_swap(fasu(rs), fasu(rs), false,   \
                                                  false);                      \
      rs = uasf(pr_[0]) + uasf(pr_[1]);                                        \
    }                                                                          \
    l_run = l_run * alpha + rs;                                                \
    m_run = mn;                                                                \
    _Pragma("unroll") for (int i = 0; i < 16; ++i) o0[i] *= alpha;             \
    _Pragma("unroll") for (int i = 0; i < 16; ++i) o1[i] *= alpha;             \
    /* P -> PV B-frags in-register: rX = swap(low_word, high_word);        */  \
    /* frag words = [rA[0], rB[0], rA[1], rB[1]]                           */  \
    bf16x8 pb0, pb1, pb2, pb3;                                                 \
    {                                                                          \
      unsigned int w0 = cvt_pk_bf16(S0[0], S0[1]), w1 = cvt_pk_bf16(S0[2], S0[3]);   \
      unsigned int w2 = cvt_pk_bf16(S0[4], S0[5]), w3 = cvt_pk_bf16(S0[6], S0[7]);   \
      unsigned int w4 = cvt_pk_bf16(S0[8], S0[9]), w5 = cvt_pk_bf16(S0[10], S0[11]); \
      unsigned int w6 = cvt_pk_bf16(S0[12], S0[13]),                           \
                   w7 = cvt_pk_bf16(S0[14], S0[15]);                           \
      auto rA = __builtin_amdgcn_permlane32_swap(w0, w2, false, false);        \
      auto rB = __builtin_amdgcn_permlane32_swap(w1, w3, false, false);        \
      auto rC = __builtin_amdgcn_permlane32_swap(w4, w6, false, false);        \
      auto rD = __builtin_amdgcn_permlane32_swap(w5, w7, false, false);        \
      u32x4 pw;                                                                \
      pw[0] = rA[0]; pw[1] = rB[0]; pw[2] = rA[1]; pw[3] = rB[1];              \
      pb0 = __builtin_bit_cast(bf16x8, pw);                                    \
      pw[0] = rC[0]; pw[1] = rD[0]; pw[2] = rC[1]; pw[3] = rD[1];              \
      pb1 = __builtin_bit_cast(bf16x8, pw);                                    \
    }                                                                          \
    {                                                                          \
      unsigned int w0 = cvt_pk_bf16(S1[0], S1[1]), w1 = cvt_pk_bf16(S1[2], S1[3]);   \
      unsigned int w2 = cvt_pk_bf16(S1[4], S1[5]), w3 = cvt_pk_bf16(S1[6], S1[7]);   \
      unsigned int w4 = cvt_pk_bf16(S1[8], S1[9]), w5 = cvt_pk_bf16(S1[10], S1[11]); \
      unsigned int w6 = cvt_pk_bf16(S1[12], S1[13]),                           \
                   w7 = cvt_pk_bf16(S1[14], S1[15]);                           \
      auto rA = __builtin_amdgcn_permlane32_swap(w0, w2, false, false);        \
      auto rB = __builtin_amdgcn_permlane32_swap(w1, w3, false, false);        \
      auto rC = __builtin_amdgcn_permlane32_swap(w4, w6, false, false);        \
      auto rD = __builtin_amdgcn_permlane32_swap(w5, w7, false, false);        \
      u32x4 pw;                                                                \
      pw[0] = rA[0]; pw[1] = rB[0]; pw[2] = rA[1]; pw[3] = rB[1];              \
      pb2 = __builtin_bit_cast(bf16x8, pw);                                    \
      pw[0] = rC[0]; pw[1] = rD[0]; pw[2] = rC[1]; pw[3] = rD[1];              \
      pb3 = __builtin_bit_cast(bf16x8, pw);                                    \
    }                                                                          \
    /* O^T += V^T P^T (A = V-frag, B = P-frag) */                              \
    __builtin_amdgcn_s_setprio(1);                                             \
    {                                                                          \
      bf16x8 vf;                                                               \
      FRAG(vf, sVc, 0, 0 + hi) o0 = mfma32(vf, pb0, o0);                       \
      FRAG(vf, sVc, 0, 2 + hi) o0 = mfma32(vf, pb1, o0);                       \
      FRAG(vf, sVc, 0, 4 + hi) o0 = mfma32(vf, pb2, o0);                       \
      FRAG(vf, sVc, 0, 6 + hi) o0 = mfma32(vf, pb3, o0);                       \
      FRAG(vf, sVc, 32, 0 + hi) o1 = mfma32(vf, pb0, o1);                      \
      FRAG(vf, sVc, 32, 2 + hi) o1 = mfma32(vf, pb1, o1);                      \
      FRAG(vf, sVc, 32, 4 + hi) o1 = mfma32(vf, pb2, o1);                      \
      FRAG(vf, sVc, 32, 6 + hi) o1 = mfma32(vf, pb3, o1);                      \
    }                                                                          \
    __builtin_amdgcn_s_setprio(0);                                             \
    if ((T) != NT - 1) {                                                       \
      /* drain only the 4 oldest vmem ops (this tile's gload_lds); the 8 */    \
      /* bias loads (newest) stay in flight across the barrier */              \
      asm volatile("s_waitcnt vmcnt(8)" ::: "memory");                         \
      __builtin_amdgcn_s_barrier();                                            \
    }                                                                          \
  }

  for (int t = 0; t < NT; t += 2) {
    TILE_BODY(t, 0, 1, sA0, sA1, sB0, sB1)
    TILE_BODY(t + 1, 1, 0, sB0, sB1, sA0, sA1)
  }
#undef TILE_BODY
#undef STAGE
#undef LDBIAS
#undef FRAG

  // epilogue: O[q][d] = O^T / l; lane writes its q-row, d = dblk*32+8g+4*hi+i
  float inv = 1.f / l_run;
  unsigned short* orow =
      Oatt + (size_t)(b * N_ + qbase + l31) * 1024 + h * 64 + hi * 4;
#pragma unroll
  for (int g = 0; g < 4; ++g) {
    u32x2 pk0;
    pk0[0] = cvt_pk_bf16(o0[g * 4 + 0] * inv, o0[g * 4 + 1] * inv);
    pk0[1] = cvt_pk_bf16(o0[g * 4 + 2] * inv, o0[g * 4 + 3] * inv);
    *reinterpret_cast<u32x2*>(orow + g * 8) = pk0;
    u32x2 pk1;
    pk1[0] = cvt_pk_bf16(o1[g * 4 + 0] * inv, o1[g * 4 + 1] * inv);
    pk1[1] = cvt_pk_bf16(o1[g * 4 + 2] * inv, o1[g * 4 + 3] * inv);
    *reinterpret_cast<u32x2*>(orow + 32 + g * 8) = pk1;
  }
}

extern "C" void kernel_launch(void* const* d_in, const int* in_sizes, int n_in, void* d_out,
                              int out_size, void* d_ws, size_t ws_size, hipStream_t stream) {
  const float* x = (const float*)d_in[0];
  const float* bias = (const float*)d_in[1];
  const float* g = (const float*)d_in[2];
  const float* wq = (const float*)d_in[3];
  const float* wkv = (const float*)d_in[4];
  const float* wout = (const float*)d_in[5];
  float* out = (float*)d_out;

  float* ps = (float*)d_ws;
  float* pss = ps + 16 * B_ * DIM_;
  float* meanA = pss + 16 * B_ * DIM_;
  float* sclA = meanA + B_ * DIM_;
  unsigned short* xn = (unsigned short*)(sclA + B_ * DIM_);
  unsigned short* Wqkv = xn + (size_t)4096 * 1024;
  unsigned short* WoutB = Wqkv + (size_t)3072 * 1024;
  unsigned short* qkvb = WoutB + (size_t)1024 * 1024;
  unsigned short* Vt = qkvb + (size_t)4096 * 3072;
  unsigned short* Oatt = xn;  // alias: xn dead after QKV GEMM

  ln_part<<<dim3(DIM_ / 256, B_ * 16), 256, 0, stream>>>(x, ps, pss);
  ln_fin<<<dim3((B_ * DIM_) / 256), 256, 0, stream>>>(ps, pss, g, meanA, sclA);
  ln_apply<<<dim3((B_ * N_ * DIM_) / 2048), 256, 0, stream>>>(x, meanA, sclA, xn);
  cast_bf16<<<dim3((DIM_ * DIM_) / 2048), 256, 0, stream>>>(wq, Wqkv, 0.125f);
  cast_bf16<<<dim3((2 * DIM_ * DIM_) / 2048), 256, 0, stream>>>(wkv, Wqkv + (size_t)DIM_ * DIM_,
                                                                1.0f);
  cast_bf16<<<dim3((DIM_ * DIM_) / 2048), 256, 0, stream>>>(wout, WoutB, 1.0f);
  gemm_bt<false><<<dim3(3072 / 128, 4096 / 128), 256, 0, stream>>>(xn, Wqkv, qkvb, DIM_, 3072);
  transpose_v<<<dim3(N_ / 64, B_ * HEADS_), 256, 0, stream>>>(qkvb, Vt);
  flash_attn<<<dim3(512), 256, 0, stream>>>(qkvb, bias, Vt, Oatt);
  gemm_bt<true><<<dim3(1024 / 128, 4096 / 128), 256, 0, stream>>>(Oatt, WoutB, out, DIM_, 1024);
}

// Round 10
// 181.993 us; speedup vs baseline: 1.1162x; 1.1162x over previous
//
#include <hip/hip_runtime.h>
#include <hip/hip_bf16.h>
#include <stdint.h>

#define B_ 2
#define N_ 2048
#define DIM_ 1024
#define HEADS_ 16
#define DH_ 64
#define EPS_ 1e-5f

typedef __attribute__((ext_vector_type(4))) float f32x4;
typedef __attribute__((ext_vector_type(8))) float f32x8;
typedef __attribute__((ext_vector_type(16))) float f32x16;
typedef __attribute__((ext_vector_type(8))) __bf16 bf16x8;
typedef __attribute__((ext_vector_type(4))) unsigned int u32x4;
typedef __attribute__((ext_vector_type(2))) unsigned int u32x2;

__device__ __forceinline__ f32x4 mfma16(bf16x8 a, bf16x8 b, f32x4 c) {
  return __builtin_amdgcn_mfma_f32_16x16x32_bf16(a, b, c, 0, 0, 0);
}

__device__ __forceinline__ f32x16 mfma32(bf16x8 a, bf16x8 b, f32x16 c) {
  return __builtin_amdgcn_mfma_f32_32x32x16_bf16(a, b, c, 0, 0, 0);
}

__device__ __forceinline__ unsigned short f2bf(float x) {
  unsigned int u = __builtin_bit_cast(unsigned int, x);
  u += 0x7fffu + ((u >> 16) & 1u);
  return (unsigned short)(u >> 16);
}

__device__ __forceinline__ unsigned int cvt_pk_bf16(float lo, float hi) {
  unsigned int r;
  asm("v_cvt_pk_bf16_f32 %0, %1, %2" : "=v"(r) : "v"(lo), "v"(hi));
  return r;
}

__device__ __forceinline__ float uasf(unsigned int u) { return __builtin_bit_cast(float, u); }
__device__ __forceinline__ unsigned int fasu(float f) { return __builtin_bit_cast(unsigned int, f); }

__device__ __forceinline__ bf16x8 ld_frag(const unsigned short* p) {
  u32x4 v = *reinterpret_cast<const u32x4*>(p);
  return __builtin_bit_cast(bf16x8, v);
}

__device__ __forceinline__ void gload_lds16(const unsigned short* g, unsigned short* l) {
  __builtin_amdgcn_global_load_lds((const __attribute__((address_space(1))) void*)g,
                                   (__attribute__((address_space(3))) void*)l, 16, 0, 0);
}

// ---------------- LayerNorm over sequence axis ----------------
__global__ __launch_bounds__(256) void ln_part(const float* __restrict__ x,
                                               float* __restrict__ ps,
                                               float* __restrict__ pss) {
  const int d = blockIdx.x * 256 + threadIdx.x;
  const int b = blockIdx.y >> 4, sp = blockIdx.y & 15;
  const float* xp = x + (size_t)(b * N_ + sp * 128) * DIM_ + d;
  float s = 0.f, ss = 0.f;
  for (int i = 0; i < 128; ++i) {
    float v = xp[(size_t)i * DIM_];
    s += v;
    ss += v * v;
  }
  int c = b * DIM_ + d;
  ps[sp * (B_ * DIM_) + c] = s;
  pss[sp * (B_ * DIM_) + c] = ss;
}

__global__ void ln_fin(const float* __restrict__ ps, const float* __restrict__ pss,
                       const float* __restrict__ g, float* __restrict__ meanA,
                       float* __restrict__ sclA) {
  int c = blockIdx.x * 256 + threadIdx.x;
  float s = 0.f, ss = 0.f;
#pragma unroll
  for (int sp = 0; sp < 16; ++sp) {
    s += ps[sp * (B_ * DIM_) + c];
    ss += pss[sp * (B_ * DIM_) + c];
  }
  float m = s * (1.f / N_);
  float v = ss * (1.f / N_) - m * m;
  meanA[c] = m;
  sclA[c] = rsqrtf(fmaxf(v, EPS_)) * g[c & (DIM_ - 1)];
}

__global__ __launch_bounds__(256) void ln_apply(const float* __restrict__ x,
                                                const float* __restrict__ meanA,
                                                const float* __restrict__ sclA,
                                                unsigned short* __restrict__ xn) {
  size_t t = (size_t)blockIdx.x * 256 + threadIdx.x;
  size_t base = t * 8;
  int d0 = (int)(base & (DIM_ - 1));
  int b = base >= (size_t)N_ * DIM_;
  int c = b * DIM_ + d0;
  const float4* xp = reinterpret_cast<const float4*>(x + base);
  const float4* mp = reinterpret_cast<const float4*>(meanA + c);
  const float4* sp = reinterpret_cast<const float4*>(sclA + c);
  float4 x0 = xp[0], x1 = xp[1];
  float4 m0 = mp[0], m1 = mp[1];
  float4 s0 = sp[0], s1 = sp[1];
  union {
    unsigned short u[8];
    u32x4 v;
  } o;
  o.u[0] = f2bf((x0.x - m0.x) * s0.x);
  o.u[1] = f2bf((x0.y - m0.y) * s0.y);
  o.u[2] = f2bf((x0.z - m0.z) * s0.z);
  o.u[3] = f2bf((x0.w - m0.w) * s0.w);
  o.u[4] = f2bf((x1.x - m1.x) * s1.x);
  o.u[5] = f2bf((x1.y - m1.y) * s1.y);
  o.u[6] = f2bf((x1.z - m1.z) * s1.z);
  o.u[7] = f2bf((x1.w - m1.w) * s1.w);
  *reinterpret_cast<u32x4*>(xn + base) = o.v;
}

// ---------------- fp32 -> bf16 weight cast (optional scale) ----------------
__global__ __launch_bounds__(256) void cast_bf16(const float* __restrict__ src,
                                                 unsigned short* __restrict__ dst, float scale) {
  size_t t = (size_t)blockIdx.x * 256 + threadIdx.x;
  size_t base = t * 8;
  const float4* sp = reinterpret_cast<const float4*>(src + base);
  float4 a = sp[0], b4 = sp[1];
  union {
    unsigned short u[8];
    u32x4 v;
  } o;
  o.u[0] = f2bf(a.x * scale);
  o.u[1] = f2bf(a.y * scale);
  o.u[2] = f2bf(a.z * scale);
  o.u[3] = f2bf(a.w * scale);
  o.u[4] = f2bf(b4.x * scale);
  o.u[5] = f2bf(b4.y * scale);
  o.u[6] = f2bf(b4.z * scale);
  o.u[7] = f2bf(b4.w * scale);
  *reinterpret_cast<u32x4*>(dst + base) = o.v;
}

// ---------------- GEMM: C[M,Nc] = A[M,K]bf16 * W[Nc,K]bf16^T ----------------
template <bool OUT_F32>
__global__ __launch_bounds__(256) void gemm_bt(const unsigned short* __restrict__ A,
                                               const unsigned short* __restrict__ W,
                                               void* __restrict__ Cout, int K, int ldc) {
  __shared__ unsigned short sA[128 * 64];
  __shared__ unsigned short sB[128 * 64];
  const int tid = threadIdx.x, lane = tid & 63, w = tid >> 6;
  const int wm = w >> 1, wn = w & 1;
  const int l15 = lane & 15, l4 = lane >> 4;
  const int m0 = blockIdx.y * 128, n0 = blockIdx.x * 128;
  f32x4 acc[4][4] = {};
  for (int kt = 0; kt < K; kt += 64) {
    __syncthreads();
#pragma unroll
    for (int p = 0; p < 4; ++p) {
      int flat = p * 256 + tid;
      int row = flat >> 3, c = flat & 7;
      int cs = c ^ (row & 7);
      gload_lds16(A + (size_t)(m0 + row) * K + kt + cs * 8, sA + (size_t)(p * 256 + w * 64) * 8);
      gload_lds16(W + (size_t)(n0 + row) * K + kt + cs * 8, sB + (size_t)(p * 256 + w * 64) * 8);
    }
    __syncthreads();
#pragma unroll
    for (int kk = 0; kk < 2; ++kk) {
      bf16x8 af[4], bfr[4];
#pragma unroll
      for (int i = 0; i < 4; ++i) {
        int rowA = wm * 64 + i * 16 + l15;
        af[i] = ld_frag(sA + rowA * 64 + (((kk * 4 + l4) ^ (rowA & 7)) * 8));
        int rowB = wn * 64 + i * 16 + l15;
        bfr[i] = ld_frag(sB + rowB * 64 + (((kk * 4 + l4) ^ (rowB & 7)) * 8));
      }
#pragma unroll
      for (int i = 0; i < 4; ++i)
#pragma unroll
        for (int j = 0; j < 4; ++j) acc[i][j] = mfma16(af[i], bfr[j], acc[i][j]);
    }
  }
#pragma unroll
  for (int i = 0; i < 4; ++i)
#pragma unroll
    for (int j = 0; j < 4; ++j)
#pragma unroll
      for (int r = 0; r < 4; ++r) {
        size_t off =
            (size_t)(m0 + wm * 64 + i * 16 + l4 * 4 + r) * ldc + (n0 + wn * 64 + j * 16 + l15);
        if (OUT_F32)
          ((float*)Cout)[off] = acc[i][j][r];
        else
          ((unsigned short*)Cout)[off] = f2bf(acc[i][j][r]);
      }
}

// ---------------- V transpose: qkv v-block -> Vt[b][h][dh][n] ----------------
__global__ __launch_bounds__(256) void transpose_v(const unsigned short* __restrict__ qkv,
                                                   unsigned short* __restrict__ Vt) {
  __shared__ unsigned short tt[64][65];
  const int tid = threadIdx.x;
  const int h = blockIdx.y >> 1, b = blockIdx.y & 1;
  const int n0 = blockIdx.x * 64;
  const unsigned short* src = qkv + (size_t)(b * N_ + n0) * 3072 + 2048 + h * 64;
#pragma unroll
  for (int i = 0; i < 16; ++i) {
    int idx = i * 256 + tid;
    int r = idx >> 6, c = idx & 63;
    tt[r][c] = src[(size_t)r * 3072 + c];
  }
  __syncthreads();
  unsigned short* dst = Vt + (size_t)(b * HEADS_ + h) * 64 * N_ + n0;
#pragma unroll
  for (int i = 0; i < 16; ++i) {
    int idx = i * 256 + tid;
    int dh = idx >> 6, nn = idx & 63;
    dst[(size_t)dh * N_ + nn] = tt[nn][dh];
  }
}

// ---------------- Flash attention (32x32 swapped, LDS-staged bias) ----------
// Same structure as the passing 32x32 in-register kernel; ONLY the bias path
// changes: each wave stages its own [32 q][64 key] fp32 bias slice into LDS
// via 8 COALESCED gload_lds (4 rows x 256B per instr = 8 segments, vs 32
// segments/instr for the per-lane scattered loads), one tile ahead,
// single-buffered (wave-private slice; lgkmcnt(0)+sched_barrier fences reads
// before overwrite issue). C-operand built from 8 chunk-XOR-swizzled
// ds_read_b128 (source pre-swizzled: slot s of row r holds global chunk
// s^(r&15); coalescing preserved since XOR permutes within the 256B row).
__global__ __launch_bounds__(256, 2) void flash_attn(const unsigned short* __restrict__ qkv,
                                                     const float* __restrict__ bias,
                                                     const unsigned short* __restrict__ Vt,
                                                     unsigned short* __restrict__ Oatt) {
  __shared__ unsigned short sK[2][64 * 64];
  __shared__ unsigned short sV[2][64 * 64];
  __shared__ float sBias[4][32 * 64];  // per-wave slice, swizzled chunks

  const int tid = threadIdx.x, lane = tid & 63, w = tid >> 6;  // w in 0..3
  const int l31 = lane & 31, hi = lane >> 5;
  const int l15x = lane & 15, ln4 = lane >> 4;
  const int sw16 = l31 & 15;
  // XCD swizzle: bh = id&31 -> (b,h); id%8 = h%8 so both b of a head (and all
  // its i-blocks) share an XCD.
  const int r = blockIdx.x;
  const int bh = r & 31, iblk = r >> 5;
  const int h = bh & 15, b = bh >> 4;
  const int i0 = iblk * 128;
  const int qbase = i0 + w * 32;

  const unsigned short* Kg = qkv + (size_t)b * N_ * 3072 + 1024 + h * 64;
  const unsigned short* VtB = Vt + (size_t)(b * HEADS_ + h) * 64 * N_;
  const float* bias_h = bias + (size_t)h * N_ * N_;

  // K/V staging (cooperative, unchanged)
  const int row0 = tid >> 3, c0 = tid & 7;
  const int cs0 = c0 ^ (row0 & 7);
  const unsigned short* KgS = Kg + (size_t)row0 * 3072 + cs0 * 8;
  const unsigned short* VtS = VtB + (size_t)row0 * N_ + cs0 * 8;

#define STAGE(BUF, JN)                                                          \
  gload_lds16(KgS + (size_t)(JN) * 3072, sK[BUF] + w * 512);                    \
  gload_lds16(KgS + (size_t)(JN) * 3072 + 32 * 3072, sK[BUF] + 2048 + w * 512); \
  gload_lds16(VtS + (JN), sV[BUF] + w * 512);                                   \
  gload_lds16(VtS + (JN) + 32 * (size_t)N_, sV[BUF] + 2048 + w * 512);

  // Bias staging: instr i covers rows qbase + i*4 + ln4, chunk (l15x ^ rloc),
  // dest linear (base + lane*16). rloc&15 identical for i and i+4 -> 4 ptrs.
  unsigned short* sBw = reinterpret_cast<unsigned short*>(sBias[w]);
  const float* bp0 = bias_h + (size_t)(qbase + 0 + ln4) * N_ + ((l15x ^ (0 + ln4)) << 2);
  const float* bp1 = bias_h + (size_t)(qbase + 4 + ln4) * N_ + ((l15x ^ (4 + ln4)) << 2);
  const float* bp2 = bias_h + (size_t)(qbase + 8 + ln4) * N_ + ((l15x ^ (8 + ln4)) << 2);
  const float* bp3 = bias_h + (size_t)(qbase + 12 + ln4) * N_ + ((l15x ^ (12 + ln4)) << 2);

#define STAGE_BIAS(JN)                                                           \
  gload_lds16((const unsigned short*)(bp0 + (JN)), sBw + 0 * 512);               \
  gload_lds16((const unsigned short*)(bp1 + (JN)), sBw + 1 * 512);               \
  gload_lds16((const unsigned short*)(bp2 + (JN)), sBw + 2 * 512);               \
  gload_lds16((const unsigned short*)(bp3 + (JN)), sBw + 3 * 512);               \
  gload_lds16((const unsigned short*)(bp0 + 16 * N_ + (JN)), sBw + 4 * 512);     \
  gload_lds16((const unsigned short*)(bp1 + 16 * N_ + (JN)), sBw + 5 * 512);     \
  gload_lds16((const unsigned short*)(bp2 + 16 * N_ + (JN)), sBw + 6 * 512);     \
  gload_lds16((const unsigned short*)(bp3 + 16 * N_ + (JN)), sBw + 7 * 512);

// C-block from LDS bias: C[reg rr] = bias[q=l31][CB*4 + 8*(rr>>2)+4*hi+(rr&3)]
// chunk cg = CB + 2g + hi lives at slot cg ^ sw16 of row l31.
#define LDBIAS_LDS(DST, CB)                                                      \
  {                                                                              \
    const float* myB_ = sBias[w] + l31 * 64;                                     \
    f32x4 t0 = *reinterpret_cast<const f32x4*>(myB_ + ((((CB) + 0 + hi) ^ sw16) << 2)); \
    f32x4 t1 = *reinterpret_cast<const f32x4*>(myB_ + ((((CB) + 2 + hi) ^ sw16) << 2)); \
    f32x4 t2 = *reinterpret_cast<const f32x4*>(myB_ + ((((CB) + 4 + hi) ^ sw16) << 2)); \
    f32x4 t3 = *reinterpret_cast<const f32x4*>(myB_ + ((((CB) + 6 + hi) ^ sw16) << 2)); \
    f32x8 u0_ = __builtin_shufflevector(t0, t1, 0, 1, 2, 3, 4, 5, 6, 7);         \
    f32x8 u1_ = __builtin_shufflevector(t2, t3, 0, 1, 2, 3, 4, 5, 6, 7);         \
    DST = __builtin_shufflevector(u0_, u1_, 0, 1, 2, 3, 4, 5, 6, 7, 8, 9, 10,    \
                                  11, 12, 13, 14, 15);                           \
  }

// frag read from swizzled LDS tile: row = RB + l31, 16B chunk CH (logical)
#define FRAG(OUT, SRC, RB, CH)                                          \
  {                                                                     \
    int row_ = (RB) + l31;                                              \
    OUT = ld_frag((SRC) + row_ * 64 + (((CH) ^ (row_ & 7)) * 8));       \
  }

  // Q B-frags: qfK covers d = K*16 + hi*8 .. +7 for q = qbase + l31
  bf16x8 qf0, qf1, qf2, qf3;
  {
    const unsigned short* Qg =
        qkv + (size_t)(b * N_ + qbase + l31) * 3072 + h * 64 + hi * 8;
    qf0 = ld_frag(Qg);
    qf1 = ld_frag(Qg + 16);
    qf2 = ld_frag(Qg + 32);
    qf3 = ld_frag(Qg + 48);
  }

  f32x16 o0 = {}, o1 = {};  // O^T d-blocks 0..31 / 32..63
  float m_run = -1e30f, l_run = 0.f;

  // prologue: stage K/V + bias for tile 0 (drained at loop-top vmcnt(0))
  STAGE(0, 0)
  STAGE_BIAS(0)

  const int NT = N_ / 64;

#define TILE_BODY(T, CUR, NXT)                                                 \
  {                                                                            \
    asm volatile("s_waitcnt vmcnt(0)" ::: "memory");                           \
    __builtin_amdgcn_s_barrier();                                              \
    f32x16 s0_, s1_;                                                           \
    LDBIAS_LDS(s0_, 0)                                                         \
    LDBIAS_LDS(s1_, 8)                                                         \
    asm volatile("s_waitcnt lgkmcnt(0)" ::: "memory");                         \
    __builtin_amdgcn_sched_barrier(0); /* bias regs live before overwrite */   \
    if ((T) + 1 < NT) {                                                        \
      const size_t jn = (size_t)((T) + 1) * 64;                                \
      STAGE_BIAS(jn)                                                           \
      STAGE(NXT, jn)                                                           \
      __builtin_amdgcn_sched_barrier(0); /* keep prefetch ahead of compute */  \
    }                                                                          \
    const unsigned short* sKc = sK[CUR];                                       \
    const unsigned short* sVc = sV[CUR];                                       \
    /* S^T = K Q^T + bias (bias in s0_/s1_ = C-operand) */                     \
    __builtin_amdgcn_s_setprio(1);                                             \
    {                                                                          \
      bf16x8 kf;                                                               \
      FRAG(kf, sKc, 0, 0 + hi) s0_ = mfma32(kf, qf0, s0_);                     \
      FRAG(kf, sKc, 0, 2 + hi) s0_ = mfma32(kf, qf1, s0_);                     \
      FRAG(kf, sKc, 0, 4 + hi) s0_ = mfma32(kf, qf2, s0_);                     \
      FRAG(kf, sKc, 0, 6 + hi) s0_ = mfma32(kf, qf3, s0_);                     \
      FRAG(kf, sKc, 32, 0 + hi) s1_ = mfma32(kf, qf0, s1_);                    \
      FRAG(kf, sKc, 32, 2 + hi) s1_ = mfma32(kf, qf1, s1_);                    \
      FRAG(kf, sKc, 32, 4 + hi) s1_ = mfma32(kf, qf2, s1_);                    \
      FRAG(kf, sKc, 32, 6 + hi) s1_ = mfma32(kf, qf3, s1_);                    \
    }                                                                          \
    __builtin_amdgcn_s_setprio(0);                                             \
    /* online softmax, fully in-register (lane pair l <-> l^32 shares q) */    \
    float mx = s0_[0];                                                         \
    _Pragma("unroll") for (int i = 1; i < 16; ++i) mx = fmaxf(mx, s0_[i]);     \
    _Pragma("unroll") for (int i = 0; i < 16; ++i) mx = fmaxf(mx, s1_[i]);     \
    {                                                                          \
      auto pr_ = __builtin_amdgcn_permlane32_swap(fasu(mx), fasu(mx), false,   \
                                                  false);                      \
      mx = fmaxf(uasf(pr_[0]), uasf(pr_[1]));                                  \
    }                                                                          \
    float mn = fmaxf(m_run, mx);                                               \
    float alpha = __expf(m_run - mn);                                          \
    _Pragma("unroll") for (int i = 0; i < 16; ++i) s0_[i] = __expf(s0_[i] - mn); \
    _Pragma("unroll") for (int i = 0; i < 16; ++i) s1_[i] = __expf(s1_[i] - mn); \
    float rs = 0.f;                                                            \
    _Pragma("unroll") for (int i = 0; i < 16; ++i) rs += s0_[i];               \
    _Pragma("unroll") for (int i = 0; i < 16; ++i) rs += s1_[i];               \
    {                                                                          \
      auto pr_ = __builtin_amdgcn_permlane32_swap(fasu(rs), fasu(rs), false,   \
                                                  false);                      \
      rs = uasf(pr_[0]) + uasf(pr_[1]);                                        \
    }                                                                          \
    l_run = l_run * alpha + rs;                                                \
    m_run = mn;                                                                \
    _Pragma("unroll") for (int i = 0; i < 16; ++i) o0[i] *= alpha;             \
    _Pragma("unroll") for (int i = 0; i < 16; ++i) o1[i] *= alpha;             \
    /* P -> PV B-frags in-register: rX = swap(low_word, high_word);        */  \
    /* frag words = [rA[0], rB[0], rA[1], rB[1]]                           */  \
    bf16x8 pb0, pb1, pb2, pb3;                                                 \
    {                                                                          \
      unsigned int w0 = cvt_pk_bf16(s0_[0], s0_[1]), w1 = cvt_pk_bf16(s0_[2], s0_[3]);   \
      unsigned int w2 = cvt_pk_bf16(s0_[4], s0_[5]), w3 = cvt_pk_bf16(s0_[6], s0_[7]);   \
      unsigned int w4 = cvt_pk_bf16(s0_[8], s0_[9]), w5 = cvt_pk_bf16(s0_[10], s0_[11]); \
      unsigned int w6 = cvt_pk_bf16(s0_[12], s0_[13]),                         \
                   w7 = cvt_pk_bf16(s0_[14], s0_[15]);                         \
      auto rA = __builtin_amdgcn_permlane32_swap(w0, w2, false, false);        \
      auto rB = __builtin_amdgcn_permlane32_swap(w1, w3, false, false);        \
      auto rC = __builtin_amdgcn_permlane32_swap(w4, w6, false, false);        \
      auto rD = __builtin_amdgcn_permlane32_swap(w5, w7, false, false);        \
      u32x4 pw;                                                                \
      pw[0] = rA[0]; pw[1] = rB[0]; pw[2] = rA[1]; pw[3] = rB[1];              \
      pb0 = __builtin_bit_cast(bf16x8, pw);                                    \
      pw[0] = rC[0]; pw[1] = rD[0]; pw[2] = rC[1]; pw[3] = rD[1];              \
      pb1 = __builtin_bit_cast(bf16x8, pw);                                    \
    }                                                                          \
    {                                                                          \
      unsigned int w0 = cvt_pk_bf16(s1_[0], s1_[1]), w1 = cvt_pk_bf16(s1_[2], s1_[3]);   \
      unsigned int w2 = cvt_pk_bf16(s1_[4], s1_[5]), w3 = cvt_pk_bf16(s1_[6], s1_[7]);   \
      unsigned int w4 = cvt_pk_bf16(s1_[8], s1_[9]), w5 = cvt_pk_bf16(s1_[10], s1_[11]); \
      unsigned int w6 = cvt_pk_bf16(s1_[12], s1_[13]),                         \
                   w7 = cvt_pk_bf16(s1_[14], s1_[15]);                         \
      auto rA = __builtin_amdgcn_permlane32_swap(w0, w2, false, false);        \
      auto rB = __builtin_amdgcn_permlane32_swap(w1, w3, false, false);        \
      auto rC = __builtin_amdgcn_permlane32_swap(w4, w6, false, false);        \
      auto rD = __builtin_amdgcn_permlane32_swap(w5, w7, false, false);        \
      u32x4 pw;                                                                \
      pw[0] = rA[0]; pw[1] = rB[0]; pw[2] = rA[1]; pw[3] = rB[1];              \
      pb2 = __builtin_bit_cast(bf16x8, pw);                                    \
      pw[0] = rC[0]; pw[1] = rD[0]; pw[2] = rC[1]; pw[3] = rD[1];              \
      pb3 = __builtin_bit_cast(bf16x8, pw);                                    \
    }                                                                          \
    /* O^T += V^T P^T (A = V-frag, B = P-frag) */                              \
    __builtin_amdgcn_s_setprio(1);                                             \
    {                                                                          \
      bf16x8 vf;                                                               \
      FRAG(vf, sVc, 0, 0 + hi) o0 = mfma32(vf, pb0, o0);                       \
      FRAG(vf, sVc, 0, 2 + hi) o0 = mfma32(vf, pb1, o0);                       \
      FRAG(vf, sVc, 0, 4 + hi) o0 = mfma32(vf, pb2, o0);                       \
      FRAG(vf, sVc, 0, 6 + hi) o0 = mfma32(vf, pb3, o0);                       \
      FRAG(vf, sVc, 32, 0 + hi) o1 = mfma32(vf, pb0, o1);                      \
      FRAG(vf, sVc, 32, 2 + hi) o1 = mfma32(vf, pb1, o1);                      \
      FRAG(vf, sVc, 32, 4 + hi) o1 = mfma32(vf, pb2, o1);                      \
      FRAG(vf, sVc, 32, 6 + hi) o1 = mfma32(vf, pb3, o1);                      \
    }                                                                          \
    __builtin_amdgcn_s_setprio(0);                                             \
  }

  for (int t = 0; t < NT; t += 2) {
    TILE_BODY(t, 0, 1)
    TILE_BODY(t + 1, 1, 0)
  }
#undef TILE_BODY
#undef STAGE
#undef STAGE_BIAS
#undef LDBIAS_LDS
#undef FRAG

  // epilogue: O[q][d] = O^T / l; lane writes its q-row, d = dblk*32+8g+4*hi+i
  float inv = 1.f / l_run;
  unsigned short* orow =
      Oatt + (size_t)(b * N_ + qbase + l31) * 1024 + h * 64 + hi * 4;
#pragma unroll
  for (int g = 0; g < 4; ++g) {
    u32x2 pk0;
    pk0[0] = cvt_pk_bf16(o0[g * 4 + 0] * inv, o0[g * 4 + 1] * inv);
    pk0[1] = cvt_pk_bf16(o0[g * 4 + 2] * inv, o0[g * 4 + 3] * inv);
    *reinterpret_cast<u32x2*>(orow + g * 8) = pk0;
    u32x2 pk1;
    pk1[0] = cvt_pk_bf16(o1[g * 4 + 0] * inv, o1[g * 4 + 1] * inv);
    pk1[1] = cvt_pk_bf16(o1[g * 4 + 2] * inv, o1[g * 4 + 3] * inv);
    *reinterpret_cast<u32x2*>(orow + 32 + g * 8) = pk1;
  }
}

extern "C" void kernel_launch(void* const* d_in, const int* in_sizes, int n_in, void* d_out,
                              int out_size, void* d_ws, size_t ws_size, hipStream_t stream) {
  const float* x = (const float*)d_in[0];
  const float* bias = (const float*)d_in[1];
  const float* g = (const float*)d_in[2];
  const float* wq = (const float*)d_in[3];
  const float* wkv = (const float*)d_in[4];
  const float* wout = (const float*)d_in[5];
  float* out = (float*)d_out;

  float* ps = (float*)d_ws;
  float* pss = ps + 16 * B_ * DIM_;
  float* meanA = pss + 16 * B_ * DIM_;
  float* sclA = meanA + B_ * DIM_;
  unsigned short* xn = (unsigned short*)(sclA + B_ * DIM_);
  unsigned short* Wqkv = xn + (size_t)4096 * 1024;
  unsigned short* WoutB = Wqkv + (size_t)3072 * 1024;
  unsigned short* qkvb = WoutB + (size_t)1024 * 1024;
  unsigned short* Vt = qkvb + (size_t)4096 * 3072;
  unsigned short* Oatt = xn;  // alias: xn dead after QKV GEMM

  ln_part<<<dim3(DIM_ / 256, B_ * 16), 256, 0, stream>>>(x, ps, pss);
  ln_fin<<<dim3((B_ * DIM_) / 256), 256, 0, stream>>>(ps, pss, g, meanA, sclA);
  ln_apply<<<dim3((B_ * N_ * DIM_) / 2048), 256, 0, stream>>>(x, meanA, sclA, xn);
  cast_bf16<<<dim3((DIM_ * DIM_) / 2048), 256, 0, stream>>>(wq, Wqkv, 0.125f);
  cast_bf16<<<dim3((2 * DIM_ * DIM_) / 2048), 256, 0, stream>>>(wkv, Wqkv + (size_t)DIM_ * DIM_,
                                                                1.0f);
  cast_bf16<<<dim3((DIM_ * DIM_) / 2048), 256, 0, stream>>>(wout, WoutB, 1.0f);
  gemm_bt<false><<<dim3(3072 / 128, 4096 / 128), 256, 0, stream>>>(xn, Wqkv, qkvb, DIM_, 3072);
  transpose_v<<<dim3(N_ / 64, B_ * HEADS_), 256, 0, stream>>>(qkvb, Vt);
  flash_attn<<<dim3(512), 256, 0, stream>>>(qkvb, bias, Vt, Oatt);
  gemm_bt<true><<<dim3(1024 / 128, 4096 / 128), 256, 0, stream>>>(Oatt, WoutB, out, DIM_, 1024);
}

// Round 12
// 173.784 us; speedup vs baseline: 1.1690x; 1.0472x over previous
//
#include <hip/hip_runtime.h>
#include <hip/hip_bf16.h>
#include <stdint.h>

#define B_ 2
#define N_ 2048
#define DIM_ 1024
#define HEADS_ 16
#define DH_ 64
#define EPS_ 1e-5f

typedef __attribute__((ext_vector_type(4))) float f32x4;
typedef __attribute__((ext_vector_type(8))) float f32x8;
typedef __attribute__((ext_vector_type(16))) float f32x16;
typedef __attribute__((ext_vector_type(8))) __bf16 bf16x8;
typedef __attribute__((ext_vector_type(4))) unsigned int u32x4;
typedef __attribute__((ext_vector_type(2))) unsigned int u32x2;

__device__ __forceinline__ f32x4 mfma16(bf16x8 a, bf16x8 b, f32x4 c) {
  return __builtin_amdgcn_mfma_f32_16x16x32_bf16(a, b, c, 0, 0, 0);
}

__device__ __forceinline__ f32x16 mfma32(bf16x8 a, bf16x8 b, f32x16 c) {
  return __builtin_amdgcn_mfma_f32_32x32x16_bf16(a, b, c, 0, 0, 0);
}

__device__ __forceinline__ unsigned short f2bf(float x) {
  unsigned int u = __builtin_bit_cast(unsigned int, x);
  u += 0x7fffu + ((u >> 16) & 1u);
  return (unsigned short)(u >> 16);
}

__device__ __forceinline__ unsigned int cvt_pk_bf16(float lo, float hi) {
  unsigned int r;
  asm("v_cvt_pk_bf16_f32 %0, %1, %2" : "=v"(r) : "v"(lo), "v"(hi));
  return r;
}

__device__ __forceinline__ float uasf(unsigned int u) { return __builtin_bit_cast(float, u); }
__device__ __forceinline__ unsigned int fasu(float f) { return __builtin_bit_cast(unsigned int, f); }

__device__ __forceinline__ bf16x8 ld_frag(const unsigned short* p) {
  u32x4 v = *reinterpret_cast<const u32x4*>(p);
  return __builtin_bit_cast(bf16x8, v);
}

__device__ __forceinline__ void gload_lds16(const unsigned short* g, unsigned short* l) {
  __builtin_amdgcn_global_load_lds((const __attribute__((address_space(1))) void*)g,
                                   (__attribute__((address_space(3))) void*)l, 16, 0, 0);
}

// ---------------- LayerNorm over sequence axis ----------------
__global__ __launch_bounds__(256) void ln_part(const float* __restrict__ x,
                                               float* __restrict__ ps,
                                               float* __restrict__ pss) {
  const int d = blockIdx.x * 256 + threadIdx.x;
  const int b = blockIdx.y >> 4, sp = blockIdx.y & 15;
  const float* xp = x + (size_t)(b * N_ + sp * 128) * DIM_ + d;
  float s = 0.f, ss = 0.f;
  for (int i = 0; i < 128; ++i) {
    float v = xp[(size_t)i * DIM_];
    s += v;
    ss += v * v;
  }
  int c = b * DIM_ + d;
  ps[sp * (B_ * DIM_) + c] = s;
  pss[sp * (B_ * DIM_) + c] = ss;
}

__global__ void ln_fin(const float* __restrict__ ps, const float* __restrict__ pss,
                       const float* __restrict__ g, float* __restrict__ meanA,
                       float* __restrict__ sclA) {
  int c = blockIdx.x * 256 + threadIdx.x;
  float s = 0.f, ss = 0.f;
#pragma unroll
  for (int sp = 0; sp < 16; ++sp) {
    s += ps[sp * (B_ * DIM_) + c];
    ss += pss[sp * (B_ * DIM_) + c];
  }
  float m = s * (1.f / N_);
  float v = ss * (1.f / N_) - m * m;
  meanA[c] = m;
  sclA[c] = rsqrtf(fmaxf(v, EPS_)) * g[c & (DIM_ - 1)];
}

__global__ __launch_bounds__(256) void ln_apply(const float* __restrict__ x,
                                                const float* __restrict__ meanA,
                                                const float* __restrict__ sclA,
                                                unsigned short* __restrict__ xn) {
  size_t t = (size_t)blockIdx.x * 256 + threadIdx.x;
  size_t base = t * 8;
  int d0 = (int)(base & (DIM_ - 1));
  int b = base >= (size_t)N_ * DIM_;
  int c = b * DIM_ + d0;
  const float4* xp = reinterpret_cast<const float4*>(x + base);
  const float4* mp = reinterpret_cast<const float4*>(meanA + c);
  const float4* sp = reinterpret_cast<const float4*>(sclA + c);
  float4 x0 = xp[0], x1 = xp[1];
  float4 m0 = mp[0], m1 = mp[1];
  float4 s0 = sp[0], s1 = sp[1];
  union {
    unsigned short u[8];
    u32x4 v;
  } o;
  o.u[0] = f2bf((x0.x - m0.x) * s0.x);
  o.u[1] = f2bf((x0.y - m0.y) * s0.y);
  o.u[2] = f2bf((x0.z - m0.z) * s0.z);
  o.u[3] = f2bf((x0.w - m0.w) * s0.w);
  o.u[4] = f2bf((x1.x - m1.x) * s1.x);
  o.u[5] = f2bf((x1.y - m1.y) * s1.y);
  o.u[6] = f2bf((x1.z - m1.z) * s1.z);
  o.u[7] = f2bf((x1.w - m1.w) * s1.w);
  *reinterpret_cast<u32x4*>(xn + base) = o.v;
}

// ---------------- fp32 -> bf16 weight cast (optional scale) ----------------
__global__ __launch_bounds__(256) void cast_bf16(const float* __restrict__ src,
                                                 unsigned short* __restrict__ dst, float scale) {
  size_t t = (size_t)blockIdx.x * 256 + threadIdx.x;
  size_t base = t * 8;
  const float4* sp = reinterpret_cast<const float4*>(src + base);
  float4 a = sp[0], b4 = sp[1];
  union {
    unsigned short u[8];
    u32x4 v;
  } o;
  o.u[0] = f2bf(a.x * scale);
  o.u[1] = f2bf(a.y * scale);
  o.u[2] = f2bf(a.z * scale);
  o.u[3] = f2bf(a.w * scale);
  o.u[4] = f2bf(b4.x * scale);
  o.u[5] = f2bf(b4.y * scale);
  o.u[6] = f2bf(b4.z * scale);
  o.u[7] = f2bf(b4.w * scale);
  *reinterpret_cast<u32x4*>(dst + base) = o.v;
}

// ---------------- GEMM: C[M,Nc] = A[M,K]bf16 * W[Nc,K]bf16^T ----------------
template <bool OUT_F32>
__global__ __launch_bounds__(256) void gemm_bt(const unsigned short* __restrict__ A,
                                               const unsigned short* __restrict__ W,
                                               void* __restrict__ Cout, int K, int ldc) {
  __shared__ unsigned short sA[128 * 64];
  __shared__ unsigned short sB[128 * 64];
  const int tid = threadIdx.x, lane = tid & 63, w = tid >> 6;
  const int wm = w >> 1, wn = w & 1;
  const int l15 = lane & 15, l4 = lane >> 4;
  const int m0 = blockIdx.y * 128, n0 = blockIdx.x * 128;
  f32x4 acc[4][4] = {};
  for (int kt = 0; kt < K; kt += 64) {
    __syncthreads();
#pragma unroll
    for (int p = 0; p < 4; ++p) {
      int flat = p * 256 + tid;
      int row = flat >> 3, c = flat & 7;
      int cs = c ^ (row & 7);
      gload_lds16(A + (size_t)(m0 + row) * K + kt + cs * 8, sA + (size_t)(p * 256 + w * 64) * 8);
      gload_lds16(W + (size_t)(n0 + row) * K + kt + cs * 8, sB + (size_t)(p * 256 + w * 64) * 8);
    }
    __syncthreads();
#pragma unroll
    for (int kk = 0; kk < 2; ++kk) {
      bf16x8 af[4], bfr[4];
#pragma unroll
      for (int i = 0; i < 4; ++i) {
        int rowA = wm * 64 + i * 16 + l15;
        af[i] = ld_frag(sA + rowA * 64 + (((kk * 4 + l4) ^ (rowA & 7)) * 8));
        int rowB = wn * 64 + i * 16 + l15;
        bfr[i] = ld_frag(sB + rowB * 64 + (((kk * 4 + l4) ^ (rowB & 7)) * 8));
      }
#pragma unroll
      for (int i = 0; i < 4; ++i)
#pragma unroll
        for (int j = 0; j < 4; ++j) acc[i][j] = mfma16(af[i], bfr[j], acc[i][j]);
    }
  }
#pragma unroll
  for (int i = 0; i < 4; ++i)
#pragma unroll
    for (int j = 0; j < 4; ++j)
#pragma unroll
      for (int r = 0; r < 4; ++r) {
        size_t off =
            (size_t)(m0 + wm * 64 + i * 16 + l4 * 4 + r) * ldc + (n0 + wn * 64 + j * 16 + l15);
        if (OUT_F32)
          ((float*)Cout)[off] = acc[i][j][r];
        else
          ((unsigned short*)Cout)[off] = f2bf(acc[i][j][r]);
      }
}

// ---------------- V transpose: qkv v-block -> Vt[b][h][dh][n] ----------------
__global__ __launch_bounds__(256) void transpose_v(const unsigned short* __restrict__ qkv,
                                                   unsigned short* __restrict__ Vt) {
  __shared__ unsigned short tt[64][65];
  const int tid = threadIdx.x;
  const int h = blockIdx.y >> 1, b = blockIdx.y & 1;
  const int n0 = blockIdx.x * 64;
  const unsigned short* src = qkv + (size_t)(b * N_ + n0) * 3072 + 2048 + h * 64;
#pragma unroll
  for (int i = 0; i < 16; ++i) {
    int idx = i * 256 + tid;
    int r = idx >> 6, c = idx & 63;
    tt[r][c] = src[(size_t)r * 3072 + c];
  }
  __syncthreads();
  unsigned short* dst = Vt + (size_t)(b * HEADS_ + h) * 64 * N_ + n0;
#pragma unroll
  for (int i = 0; i < 16; ++i) {
    int idx = i * 256 + tid;
    int dh = idx >> 6, nn = idx & 63;
    dst[(size_t)dh * N_ + nn] = tt[nn][dh];
  }
}

// ---------------- Flash attention: 8 waves, 160KB LDS, 128-key pairs --------
// AITER-shaped: 512 thr (8 waves x 32 q = 256 q/block), grid 256 = 1 block/CU.
// Per pair p (128 keys): bias for p+1 staged (coalesced, wave-private LDS,
// 16 KB/wave) right after p's bias regs are read -> full-pair (~2000cy) HBM
// cover. K/V pair tiles (16+16 KB) staged after the tail barrier (L2-hit,
// ~300cy exposed). Merged online-softmax once per 128 keys. 32x32 swapped
// MFMA + in-register softmax/P (layouts verified in rounds 9/10).
__global__ __launch_bounds__(512, 2) void flash_attn(const unsigned short* __restrict__ qkv,
                                                     const float* __restrict__ bias,
                                                     const unsigned short* __restrict__ Vt,
                                                     unsigned short* __restrict__ Oatt) {
  __shared__ unsigned short sK[128 * 64];   // 16 KB: pair of K tiles, row=key
  __shared__ unsigned short sV[64 * 128];   // 16 KB: V^T pair, row=d
  __shared__ float sBias[8][32 * 128];      // 128 KB: per-wave 32q x 128k slice

  const int tid = threadIdx.x, lane = tid & 63, w = tid >> 6;  // w in 0..7
  const int l31 = lane & 31, hi = lane >> 5;
  const int r = blockIdx.x;
  const int bh = r & 31, iblk = r >> 5;  // iblk 0..7
  const int h = bh & 15, b = bh >> 4;
  const int qbase = iblk * 256 + w * 32;

  const unsigned short* Kg = qkv + (size_t)b * N_ * 3072 + 1024 + h * 64;
  const unsigned short* VtB = Vt + (size_t)(b * HEADS_ + h) * 64 * N_;
  const float* bias_h = bias + (size_t)h * N_ * N_;

  // ---- K/V staging (cooperative, 2 gload16/thread each) ----
  const int kflat0 = tid, kflat1 = 512 + tid;
  const int krow0 = kflat0 >> 3, kc0 = (kflat0 & 7) ^ (krow0 & 7);
  const int krow1 = kflat1 >> 3, kc1 = (kflat1 & 7) ^ (krow1 & 7);
  const int vrow0 = kflat0 >> 4, vc0 = (kflat0 & 15) ^ (vrow0 & 15);
  const int vrow1 = kflat1 >> 4, vc1 = (kflat1 & 15) ^ (vrow1 & 15);
  unsigned short* sKb0 = sK + (size_t)(w * 64) * 8;
  unsigned short* sKb1 = sK + (size_t)(512 + w * 64) * 8;
  unsigned short* sVb0 = sV + (size_t)(w * 64) * 8;
  unsigned short* sVb1 = sV + (size_t)(512 + w * 64) * 8;

#define STAGE_KV(JN)                                                       \
  gload_lds16(Kg + (size_t)((JN) + krow0) * 3072 + kc0 * 8, sKb0);         \
  gload_lds16(Kg + (size_t)((JN) + krow1) * 3072 + kc1 * 8, sKb1);         \
  gload_lds16(VtB + (size_t)vrow0 * N_ + (JN) + vc0 * 8, sVb0);            \
  gload_lds16(VtB + (size_t)vrow1 * N_ + (JN) + vc1 * 8, sVb1);

  // ---- bias staging: wave-private 32q x 128k, slot s of row r holds ----
  // ---- global chunk s ^ r; dest linear = instr*1024B + lane*16B       ----
  float* sBw = sBias[w];
  unsigned short* sBw_us = reinterpret_cast<unsigned short*>(sBw);
  const int brr = lane >> 5, bsl = lane & 31;
  const float* bQ = bias_h + (size_t)qbase * N_;
#define SBI(i, JN)                                                            \
  gload_lds16((const unsigned short*)(bQ + (size_t)(2 * (i) + brr) * N_ +     \
                                      (JN) + ((bsl ^ (2 * (i) + brr)) << 2)), \
              sBw_us + (i) * 512);
#define STAGE_BIAS(JN)                                                     \
  SBI(0, JN) SBI(1, JN) SBI(2, JN) SBI(3, JN) SBI(4, JN) SBI(5, JN)        \
  SBI(6, JN) SBI(7, JN) SBI(8, JN) SBI(9, JN) SBI(10, JN) SBI(11, JN)      \
  SBI(12, JN) SBI(13, JN) SBI(14, JN) SBI(15, JN)

// C-block from LDS bias: C[rr] = bias[q=l31][CB*4 + 8*(rr>>2)+4*hi+(rr&3)]
#define LDBIAS(DST, CB)                                                        \
  {                                                                            \
    const float* myB_ = sBw + l31 * 128;                                       \
    f32x4 t0 = *reinterpret_cast<const f32x4*>(myB_ + ((((CB) + 0 + hi) ^ l31) << 2)); \
    f32x4 t1 = *reinterpret_cast<const f32x4*>(myB_ + ((((CB) + 2 + hi) ^ l31) << 2)); \
    f32x4 t2 = *reinterpret_cast<const f32x4*>(myB_ + ((((CB) + 4 + hi) ^ l31) << 2)); \
    f32x4 t3 = *reinterpret_cast<const f32x4*>(myB_ + ((((CB) + 6 + hi) ^ l31) << 2)); \
    f32x8 u0_ = __builtin_shufflevector(t0, t1, 0, 1, 2, 3, 4, 5, 6, 7);       \
    f32x8 u1_ = __builtin_shufflevector(t2, t3, 0, 1, 2, 3, 4, 5, 6, 7);       \
    DST = __builtin_shufflevector(u0_, u1_, 0, 1, 2, 3, 4, 5, 6, 7, 8, 9, 10,  \
                                  11, 12, 13, 14, 15);                         \
  }

#define FRAGK(OUT, ROWB, CH)                                              \
  {                                                                       \
    int row_ = (ROWB) + l31;                                              \
    OUT = ld_frag(sK + row_ * 64 + (((CH) ^ (row_ & 7)) * 8));            \
  }
#define FRAGV(OUT, ROWB, CH)                                              \
  {                                                                       \
    int row_ = (ROWB) + l31;                                              \
    OUT = ld_frag(sV + row_ * 128 + (((CH) ^ (row_ & 15)) * 8));          \
  }

// pack one 32-key S block into two PV B-frags (verified r9/r10)
#define PACK2(S, PLO, PHI)                                                 \
  {                                                                        \
    unsigned int w0 = cvt_pk_bf16(S[0], S[1]), w1 = cvt_pk_bf16(S[2], S[3]);     \
    unsigned int w2 = cvt_pk_bf16(S[4], S[5]), w3 = cvt_pk_bf16(S[6], S[7]);     \
    unsigned int w4 = cvt_pk_bf16(S[8], S[9]), w5 = cvt_pk_bf16(S[10], S[11]);   \
    unsigned int w6 = cvt_pk_bf16(S[12], S[13]), w7 = cvt_pk_bf16(S[14], S[15]); \
    auto rA = __builtin_amdgcn_permlane32_swap(w0, w2, false, false);      \
    auto rB = __builtin_amdgcn_permlane32_swap(w1, w3, false, false);      \
    auto rC = __builtin_amdgcn_permlane32_swap(w4, w6, false, false);      \
    auto rD = __builtin_amdgcn_permlane32_swap(w5, w7, false, false);      \
    u32x4 pw;                                                              \
    pw[0] = rA[0]; pw[1] = rB[0]; pw[2] = rA[1]; pw[3] = rB[1];            \
    PLO = __builtin_bit_cast(bf16x8, pw);                                  \
    pw[0] = rC[0]; pw[1] = rD[0]; pw[2] = rC[1]; pw[3] = rD[1];            \
    PHI = __builtin_bit_cast(bf16x8, pw);                                  \
  }

  // Q B-frags: qfK covers d = K*16 + hi*8 .. +7 for q = qbase + l31
  bf16x8 qf0, qf1, qf2, qf3;
  {
    const unsigned short* Qg =
        qkv + (size_t)(b * N_ + qbase + l31) * 3072 + h * 64 + hi * 8;
    qf0 = ld_frag(Qg);
    qf1 = ld_frag(Qg + 16);
    qf2 = ld_frag(Qg + 32);
    qf3 = ld_frag(Qg + 48);
  }

  f32x16 o0 = {}, o1 = {};
  float m_run = -1e30f, l_run = 0.f;

  // prologue: stage pair 0 (drained at loop-top vmcnt(0))
  STAGE_KV(0)
  STAGE_BIAS(0)

  const int NP = N_ / 128;  // 16 pairs
  for (int p = 0; p < NP; ++p) {
    asm volatile("s_waitcnt vmcnt(0) lgkmcnt(0)" ::: "memory");
    __builtin_amdgcn_s_barrier();

    // 1. bias regs for pair p (C-operands for the 4 S blocks)
    f32x16 SA0, SA1, SB0, SB1;
    LDBIAS(SA0, 0)
    LDBIAS(SA1, 8)
    LDBIAS(SB0, 16)
    LDBIAS(SB1, 24)
    asm volatile("s_waitcnt lgkmcnt(0)" ::: "memory");
    __builtin_amdgcn_sched_barrier(0);  // bias regs live before overwrite

    // 2. bias prefetch for pair p+1 (full-pair cover; wave-private slice)
    if (p + 1 < NP) {
      const size_t jn = (size_t)(p + 1) * 128;
      STAGE_BIAS(jn)
    }

    // 3. S^T = K Q^T + bias for both tiles of the pair
    __builtin_amdgcn_s_setprio(1);
    {
      bf16x8 kf;
      FRAGK(kf, 0, 0 + hi)  SA0 = mfma32(kf, qf0, SA0);
      FRAGK(kf, 0, 2 + hi)  SA0 = mfma32(kf, qf1, SA0);
      FRAGK(kf, 0, 4 + hi)  SA0 = mfma32(kf, qf2, SA0);
      FRAGK(kf, 0, 6 + hi)  SA0 = mfma32(kf, qf3, SA0);
      FRAGK(kf, 32, 0 + hi) SA1 = mfma32(kf, qf0, SA1);
      FRAGK(kf, 32, 2 + hi) SA1 = mfma32(kf, qf1, SA1);
      FRAGK(kf, 32, 4 + hi) SA1 = mfma32(kf, qf2, SA1);
      FRAGK(kf, 32, 6 + hi) SA1 = mfma32(kf, qf3, SA1);
      FRAGK(kf, 64, 0 + hi) SB0 = mfma32(kf, qf0, SB0);
      FRAGK(kf, 64, 2 + hi) SB0 = mfma32(kf, qf1, SB0);
      FRAGK(kf, 64, 4 + hi) SB0 = mfma32(kf, qf2, SB0);
      FRAGK(kf, 64, 6 + hi) SB0 = mfma32(kf, qf3, SB0);
      FRAGK(kf, 96, 0 + hi) SB1 = mfma32(kf, qf0, SB1);
      FRAGK(kf, 96, 2 + hi) SB1 = mfma32(kf, qf1, SB1);
      FRAGK(kf, 96, 4 + hi) SB1 = mfma32(kf, qf2, SB1);
      FRAGK(kf, 96, 6 + hi) SB1 = mfma32(kf, qf3, SB1);
    }
    __builtin_amdgcn_s_setprio(0);

    // 4. merged online softmax over 128 keys (4 parallel 15-deep chains)
    float c0 = SA0[0], c1 = SA1[0], c2 = SB0[0], c3 = SB1[0];
#pragma unroll
    for (int i = 1; i < 16; ++i) {
      c0 = fmaxf(c0, SA0[i]);
      c1 = fmaxf(c1, SA1[i]);
      c2 = fmaxf(c2, SB0[i]);
      c3 = fmaxf(c3, SB1[i]);
    }
    float mx = fmaxf(fmaxf(c0, c1), fmaxf(c2, c3));
    {
      auto pr_ = __builtin_amdgcn_permlane32_swap(fasu(mx), fasu(mx), false, false);
      mx = fmaxf(uasf(pr_[0]), uasf(pr_[1]));
    }
    float mn = fmaxf(m_run, mx);
    float alpha = __expf(m_run - mn);
#pragma unroll
    for (int i = 0; i < 16; ++i) {
      SA0[i] = __expf(SA0[i] - mn);
      SA1[i] = __expf(SA1[i] - mn);
      SB0[i] = __expf(SB0[i] - mn);
      SB1[i] = __expf(SB1[i] - mn);
    }
    float r0 = 0.f, r1 = 0.f, r2 = 0.f, r3 = 0.f;
#pragma unroll
    for (int i = 0; i < 16; ++i) {
      r0 += SA0[i];
      r1 += SA1[i];
      r2 += SB0[i];
      r3 += SB1[i];
    }
    float rs = (r0 + r1) + (r2 + r3);
    {
      auto pr_ = __builtin_amdgcn_permlane32_swap(fasu(rs), fasu(rs), false, false);
      rs = uasf(pr_[0]) + uasf(pr_[1]);
    }
    l_run = l_run * alpha + rs;
    m_run = mn;
#pragma unroll
    for (int i = 0; i < 16; ++i) {
      o0[i] *= alpha;
      o1[i] *= alpha;
    }

    // 5. P -> PV B-frags in-register
    bf16x8 pA0, pA1, pA2, pA3, pB0, pB1, pB2, pB3;
    PACK2(SA0, pA0, pA1)
    PACK2(SA1, pA2, pA3)
    PACK2(SB0, pB0, pB1)
    PACK2(SB1, pB2, pB3)

    // 6. O^T += V^T P^T over the 128-key pair
    __builtin_amdgcn_s_setprio(1);
    {
      bf16x8 vf;
      FRAGV(vf, 0, 0 + hi)   o0 = mfma32(vf, pA0, o0);
      FRAGV(vf, 0, 2 + hi)   o0 = mfma32(vf, pA1, o0);
      FRAGV(vf, 0, 4 + hi)   o0 = mfma32(vf, pA2, o0);
      FRAGV(vf, 0, 6 + hi)   o0 = mfma32(vf, pA3, o0);
      FRAGV(vf, 0, 8 + hi)   o0 = mfma32(vf, pB0, o0);
      FRAGV(vf, 0, 10 + hi)  o0 = mfma32(vf, pB1, o0);
      FRAGV(vf, 0, 12 + hi)  o0 = mfma32(vf, pB2, o0);
      FRAGV(vf, 0, 14 + hi)  o0 = mfma32(vf, pB3, o0);
      FRAGV(vf, 32, 0 + hi)  o1 = mfma32(vf, pA0, o1);
      FRAGV(vf, 32, 2 + hi)  o1 = mfma32(vf, pA1, o1);
      FRAGV(vf, 32, 4 + hi)  o1 = mfma32(vf, pA2, o1);
      FRAGV(vf, 32, 6 + hi)  o1 = mfma32(vf, pA3, o1);
      FRAGV(vf, 32, 8 + hi)  o1 = mfma32(vf, pB0, o1);
      FRAGV(vf, 32, 10 + hi) o1 = mfma32(vf, pB1, o1);
      FRAGV(vf, 32, 12 + hi) o1 = mfma32(vf, pB2, o1);
      FRAGV(vf, 32, 14 + hi) o1 = mfma32(vf, pB3, o1);
    }
    __builtin_amdgcn_s_setprio(0);

    // 7. all waves done reading K/V pair p -> stage pair p+1
    asm volatile("s_waitcnt lgkmcnt(0)" ::: "memory");
    __builtin_amdgcn_s_barrier();
    if (p + 1 < NP) {
      const size_t jn = (size_t)(p + 1) * 128;
      STAGE_KV(jn)
    }
  }
#undef STAGE_KV
#undef SBI
#undef STAGE_BIAS
#undef LDBIAS
#undef FRAGK
#undef FRAGV
#undef PACK2

  // epilogue: O[q][d] = O^T / l
  float inv = 1.f / l_run;
  unsigned short* orow =
      Oatt + (size_t)(b * N_ + qbase + l31) * 1024 + h * 64 + hi * 4;
#pragma unroll
  for (int g = 0; g < 4; ++g) {
    u32x2 pk0;
    pk0[0] = cvt_pk_bf16(o0[g * 4 + 0] * inv, o0[g * 4 + 1] * inv);
    pk0[1] = cvt_pk_bf16(o0[g * 4 + 2] * inv, o0[g * 4 + 3] * inv);
    *reinterpret_cast<u32x2*>(orow + g * 8) = pk0;
    u32x2 pk1;
    pk1[0] = cvt_pk_bf16(o1[g * 4 + 0] * inv, o1[g * 4 + 1] * inv);
    pk1[1] = cvt_pk_bf16(o1[g * 4 + 2] * inv, o1[g * 4 + 3] * inv);
    *reinterpret_cast<u32x2*>(orow + 32 + g * 8) = pk1;
  }
}

extern "C" void kernel_launch(void* const* d_in, const int* in_sizes, int n_in, void* d_out,
                              int out_size, void* d_ws, size_t ws_size, hipStream_t stream) {
  const float* x = (const float*)d_in[0];
  const float* bias = (const float*)d_in[1];
  const float* g = (const float*)d_in[2];
  const float* wq = (const float*)d_in[3];
  const float* wkv = (const float*)d_in[4];
  const float* wout = (const float*)d_in[5];
  float* out = (float*)d_out;

  float* ps = (float*)d_ws;
  float* pss = ps + 16 * B_ * DIM_;
  float* meanA = pss + 16 * B_ * DIM_;
  float* sclA = meanA + B_ * DIM_;
  unsigned short* xn = (unsigned short*)(sclA + B_ * DIM_);
  unsigned short* Wqkv = xn + (size_t)4096 * 1024;
  unsigned short* WoutB = Wqkv + (size_t)3072 * 1024;
  unsigned short* qkvb = WoutB + (size_t)1024 * 1024;
  unsigned short* Vt = qkvb + (size_t)4096 * 3072;
  unsigned short* Oatt = xn;  // alias: xn dead after QKV GEMM

  ln_part<<<dim3(DIM_ / 256, B_ * 16), 256, 0, stream>>>(x, ps, pss);
  ln_fin<<<dim3((B_ * DIM_) / 256), 256, 0, stream>>>(ps, pss, g, meanA, sclA);
  ln_apply<<<dim3((B_ * N_ * DIM_) / 2048), 256, 0, stream>>>(x, meanA, sclA, xn);
  cast_bf16<<<dim3((DIM_ * DIM_) / 2048), 256, 0, stream>>>(wq, Wqkv, 0.125f);
  cast_bf16<<<dim3((2 * DIM_ * DIM_) / 2048), 256, 0, stream>>>(wkv, Wqkv + (size_t)DIM_ * DIM_,
                                                                1.0f);
  cast_bf16<<<dim3((DIM_ * DIM_) / 2048), 256, 0, stream>>>(wout, WoutB, 1.0f);
  gemm_bt<false><<<dim3(3072 / 128, 4096 / 128), 256, 0, stream>>>(xn, Wqkv, qkvb, DIM_, 3072);
  transpose_v<<<dim3(N_ / 64, B_ * HEADS_), 256, 0, stream>>>(qkvb, Vt);
  flash_attn<<<dim3(256), 512, 0, stream>>>(qkvb, bias, Vt, Oatt);
  gemm_bt<true><<<dim3(1024 / 128, 4096 / 128), 256, 0, stream>>>(Oatt, WoutB, out, DIM_, 1024);
}